// Round 10
// baseline (333.570 us; speedup 1.0000x reference)
//
#include <hip/hip_runtime.h>
#include <math.h>

#define B_   2
#define L_   1024
#define DM   1024
#define DS   16
#define DC   4
#define DI   2048          // E*DM
#define DR   64            // DM/16
#define NTOK (B_*L_)       // 2048
#define EPSF 1e-5f
#define NC   32            // scan chunks
#define CL   (L_/NC)       // 32 steps per chunk
#define SPLITS 8           // x_proj K-splits

typedef __bf16 bf16_t;
typedef bf16_t bf16x4 __attribute__((ext_vector_type(4)));
typedef bf16_t bf16x8 __attribute__((ext_vector_type(8)));
typedef float  f32x4  __attribute__((ext_vector_type(4)));

__device__ __forceinline__ float siluf(float x){ return x / (1.f + __expf(-x)); }
__device__ __forceinline__ float softplusf(float x){ return (x > 20.f) ? x : log1pf(__expf(x)); }

__device__ __forceinline__ void gload_lds16(const void* g, void* l) {
    __builtin_amdgcn_global_load_lds(
        (const __attribute__((address_space(1))) void*)g,
        (__attribute__((address_space(3))) void*)l, 16, 0, 0);
}

// value-returning split (vector elements can't bind to references)
struct hl_t { bf16_t h, l; };
__device__ __forceinline__ hl_t split2(float v) {
    hl_t r;
    r.h = (bf16_t)v;
    r.l = (bf16_t)(v - (float)r.h);
    return r;
}

// ==== launch 1: RMSNorm (blocks 0..2047) + ALL weight splits (incl out_w) ===
#define SPLIT_IN_BLKS  ((2*DI*DM/4)/256)   // 8192
#define SPLIT_X_BLKS   ((128*DI/4)/256)    // 256
#define SPLIT_O_BLKS   ((DM*DI/4)/256)     // 2048
__global__ __launch_bounds__(256) void rms_split_all(
    const float* __restrict__ x, const float* __restrict__ w,
    bf16_t* __restrict__ uh, bf16_t* __restrict__ ul,
    const float* __restrict__ in_w, bf16_t* __restrict__ wih, bf16_t* __restrict__ wil,
    const float* __restrict__ x_w,  bf16_t* __restrict__ wxh,  bf16_t* __restrict__ wxl,
    const float* __restrict__ out_w, bf16_t* __restrict__ woh, bf16_t* __restrict__ wol)
{
    __shared__ float sred[4];
    int blk = blockIdx.x;
    int t = threadIdx.x;

    if (blk < NTOK) {                       // ---- RMSNorm row ----
        int row = blk;
        float4 v = ((const float4*)(x + (size_t)row*DM))[t];
        float ss = v.x*v.x + v.y*v.y + v.z*v.z + v.w*v.w;
        #pragma unroll
        for (int off = 32; off > 0; off >>= 1) ss += __shfl_xor(ss, off, 64);
        if ((t & 63) == 0) sred[t >> 6] = ss;
        __syncthreads();
        ss = sred[0] + sred[1] + sred[2] + sred[3];
        float rs = rsqrtf(ss * (1.f/(float)DM) + EPSF);
        float4 wv = ((const float4*)w)[t];
        float o[4];
        o[0] = v.x*rs*wv.x; o[1] = v.y*rs*wv.y; o[2] = v.z*rs*wv.z; o[3] = v.w*rs*wv.w;
        bf16x4 hv, lv;
        #pragma unroll
        for (int j = 0; j < 4; ++j) { hl_t s = split2(o[j]); hv[j] = s.h; lv[j] = s.l; }
        *(bf16x4*)(uh + (size_t)row*DM + t*4) = hv;
        *(bf16x4*)(ul + (size_t)row*DM + t*4) = lv;
        return;
    }
    blk -= NTOK;
    if (blk < SPLIT_IN_BLKS) {              // ---- in_proj_w ----
        int i = blk * 256 + t;
        float4 v = ((const float4*)in_w)[i];
        float o[4] = {v.x, v.y, v.z, v.w};
        bf16x4 hv, lv;
        #pragma unroll
        for (int j = 0; j < 4; ++j) { hl_t s = split2(o[j]); hv[j] = s.h; lv[j] = s.l; }
        ((bf16x4*)wih)[i] = hv;
        ((bf16x4*)wil)[i] = lv;
        return;
    }
    blk -= SPLIT_IN_BLKS;
    if (blk < SPLIT_X_BLKS) {               // ---- x_proj_w padded 96->128 ----
        int i = blk * 256 + t;              // over 128*DI/4
        int row = i >> 9;                   // DI/4 = 512 float4 per row
        bf16x4 hv, lv;
        if (row < 96) {
            float4 v = ((const float4*)x_w)[i];
            float o[4] = {v.x, v.y, v.z, v.w};
            #pragma unroll
            for (int j = 0; j < 4; ++j) { hl_t s = split2(o[j]); hv[j] = s.h; lv[j] = s.l; }
        } else {
            #pragma unroll
            for (int j = 0; j < 4; ++j) { hv[j] = (bf16_t)0.f; lv[j] = (bf16_t)0.f; }
        }
        ((bf16x4*)wxh)[i] = hv;
        ((bf16x4*)wxl)[i] = lv;
        return;
    }
    blk -= SPLIT_X_BLKS;
    {                                       // ---- out_proj_w ----
        int i = blk * 256 + t;              // over DM*DI/4
        float4 v = ((const float4*)out_w)[i];
        float o[4] = {v.x, v.y, v.z, v.w};
        bf16x4 hv, lv;
        #pragma unroll
        for (int j = 0; j < 4; ++j) { hl_t s = split2(o[j]); hv[j] = s.h; lv[j] = s.l; }
        ((bf16x4*)woh)[i] = hv;
        ((bf16x4*)wol)[i] = lv;
    }
}

// ---------------- split-bf16 MFMA NT GEMM, 2-phase double-buffered ---------
// Round-4 structure (no LDS swizzle — A/B'd at −2x on dt_proj, r7) PLUS
// XCD-aware block swizzle (T1): each XCD owns a contiguous n-chunk and walks
// all m-tiles, so its B-panels stay in its private L2 while A streams via L3.
// REQUIRES (non-SK): gridDim.x % 8 == 0 and gridDim.y == 16.
template<int BN, int EPI, bool SK>
__global__ __launch_bounds__(256) void gemm_mfma(
    const bf16_t* __restrict__ Ah, const bf16_t* __restrict__ Al,
    const bf16_t* __restrict__ Bh, const bf16_t* __restrict__ Bl,
    float* __restrict__ C, int ldc,
    const float* __restrict__ res,
    int M, int N, int K, int kspl)
{
    constexpr int NJ   = BN / 32;
    constexpr int WN   = BN / 2;
    constexpr int ACH  = 8;
    constexpr int BCH  = BN / 16;
    constexpr int NCH  = 2*ACH + 2*BCH;
    constexpr int PERW = NCH / 4;
    constexpr int AOFF_L = 128*32;
    constexpr int BOFF_H = 2*128*32;
    constexpr int BOFF_L = 2*128*32 + BN*32;
    constexpr int BUFSZ  = 2*128*32 + 2*BN*32;

    __shared__ bf16_t lds[2*BUFSZ];

    int t = threadIdx.x;
    int w = t >> 6, lane = t & 63;
    int wr = w >> 1, wc = w & 1;

    int bx, by;
    if (!SK) {                      // XCD swizzle (bijective: gx%8==0, gy==16)
        int bid = blockIdx.y * gridDim.x + blockIdx.x;
        int xcd = bid & 7;
        int i   = bid >> 3;
        bx = xcd * (int)(gridDim.x >> 3) + (i >> 4);
        by = i & 15;
    } else { bx = blockIdx.x; by = blockIdx.y; }

    int m0 = by * 128;
    int n0 = SK ? 0 : bx * BN;
    int k0beg = SK ? bx * kspl : 0;
    int nst = (SK ? kspl : K) >> 5;
    float* Cp = C;
    if (SK) Cp += (size_t)bx * M * BN;

    f32x4 acc[4][NJ];
    #pragma unroll
    for (int i = 0; i < 4; ++i)
        #pragma unroll
        for (int j = 0; j < NJ; ++j)
            acc[i][j] = (f32x4){0.f, 0.f, 0.f, 0.f};

    int lrow = lane >> 2;          // row within 16-row chunk
    int lcol = (lane & 3) * 8;     // k element offset
    int ar   = wr*64 + (lane & 15);
    int br   = wc*WN + (lane & 15);
    int koff = (lane >> 4) * 8;

    auto STAGE = [&](int buf, int k0) {
        int base = buf ? BUFSZ : 0;
        #pragma unroll
        for (int q = 0; q < PERW; ++q) {
            int ch = w * PERW + q;
            const bf16_t* g; int le;
            if (ch < ACH) {
                int cc = ch;
                g  = Ah + (size_t)(m0 + cc*16 + lrow)*K + k0 + lcol;
                le = cc*512 + lane*8;
            } else if (ch < 2*ACH) {
                int cc = ch - ACH;
                g  = Al + (size_t)(m0 + cc*16 + lrow)*K + k0 + lcol;
                le = AOFF_L + cc*512 + lane*8;
            } else if (ch < 2*ACH + BCH) {
                int cc = ch - 2*ACH;
                g  = Bh + (size_t)(n0 + cc*16 + lrow)*K + k0 + lcol;
                le = BOFF_H + cc*512 + lane*8;
            } else {
                int cc = ch - 2*ACH - BCH;
                g  = Bl + (size_t)(n0 + cc*16 + lrow)*K + k0 + lcol;
                le = BOFF_L + cc*512 + lane*8;
            }
            gload_lds16(g, &lds[base + le]);
        }
    };

    STAGE(0, k0beg);
    __syncthreads();
    int cur = 0;
    for (int s = 0; s < nst; ++s) {
        int k0 = k0beg + (s << 5);
        if (s + 1 < nst) STAGE(cur ^ 1, k0 + 32);
        int base = cur ? BUFSZ : 0;

        bf16x8 ah[4], al4[4], bh[NJ], bl4[NJ];
        #pragma unroll
        for (int i = 0; i < 4; ++i) {
            ah[i]  = *(const bf16x8*)&lds[base + (ar + i*16)*32 + koff];
            al4[i] = *(const bf16x8*)&lds[base + AOFF_L + (ar + i*16)*32 + koff];
        }
        #pragma unroll
        for (int j = 0; j < NJ; ++j) {
            bh[j]  = *(const bf16x8*)&lds[base + BOFF_H + (br + j*16)*32 + koff];
            bl4[j] = *(const bf16x8*)&lds[base + BOFF_L + (br + j*16)*32 + koff];
        }
        #pragma unroll
        for (int i = 0; i < 4; ++i)
            #pragma unroll
            for (int j = 0; j < NJ; ++j) {
                acc[i][j] = __builtin_amdgcn_mfma_f32_16x16x32_bf16(ah[i],  bh[j],  acc[i][j], 0, 0, 0);
                acc[i][j] = __builtin_amdgcn_mfma_f32_16x16x32_bf16(al4[i], bh[j],  acc[i][j], 0, 0, 0);
                acc[i][j] = __builtin_amdgcn_mfma_f32_16x16x32_bf16(ah[i],  bl4[j], acc[i][j], 0, 0, 0);
            }
        __syncthreads();
        cur ^= 1;
    }

    // epilogue: C/D layout col=lane&15, row=(lane>>4)*4+reg  [m89-verified]
    int rb = m0 + wr*64 + (lane >> 4)*4;
    int cb = n0 + wc*WN + (lane & 15);
    #pragma unroll
    for (int i = 0; i < 4; ++i)
        #pragma unroll
        for (int j = 0; j < NJ; ++j) {
            int col = cb + j*16;
            #pragma unroll
            for (int r = 0; r < 4; ++r) {
                int row = rb + i*16 + r;
                float v = acc[i][j][r];
                if (EPI == 2) v += res[(size_t)row*ldc + col];
                Cp[(size_t)row*ldc + col] = v;
            }
        }
}

// ==== launch 5: x_proj reduce + fused dt_proj matvec (4 tokens/block) ======
// 512 blocks (2/CU). Phase A (threads 0..127): reduce split-K partials for
// 4 tokens into LDS dt[4][64] + write bc. Phase B (all 256): each thread
// computes 8 d-cols x 4 tokens in exact fp32, softplus, coalesced stores.
__global__ __launch_bounds__(256) void dt_fuse(
    const float* __restrict__ parts,
    float* __restrict__ bc,
    const float* __restrict__ dt_w,     // [DI, DR] fp32
    const float* __restrict__ dt_b,     // [DI]
    float* __restrict__ delta)          // [NTOK, DI]
{
    __shared__ float dtsh[4][DR];       // 1 KB
    int blk = blockIdx.x;               // 0..511
    int t = threadIdx.x;
    if (t < 128) {
        int token = t >> 5;             // 0..3
        int c = (t & 31) * 4;           // 0..124
        int m = blk*4 + token;
        float4 s = {0.f, 0.f, 0.f, 0.f};
        #pragma unroll
        for (int sp = 0; sp < SPLITS; ++sp) {
            float4 v = *(const float4*)(parts + ((size_t)sp*NTOK + m)*128 + c);
            s.x += v.x; s.y += v.y; s.z += v.z; s.w += v.w;
        }
        if (c < 64) {
            *(float4*)&dtsh[token][c] = s;
        } else if (c < 96) {
            *(float4*)(bc + (size_t)m*32 + (c - 64)) = s;
        }
    }
    __syncthreads();
    // phase B: 8 d-columns per thread, 4 tokens
    for (int dd = 0; dd < 8; ++dd) {
        int d = dd*256 + t;
        float4 wv[16];
        #pragma unroll
        for (int k4 = 0; k4 < 16; ++k4)
            wv[k4] = *(const float4*)(dt_w + (size_t)d*DR + k4*4);
        float bb = dt_b[d];
        float acc[4];
        #pragma unroll
        for (int tok = 0; tok < 4; ++tok) acc[tok] = bb;
        #pragma unroll
        for (int k4 = 0; k4 < 16; ++k4) {
            #pragma unroll
            for (int tok = 0; tok < 4; ++tok) {
                acc[tok] = fmaf(wv[k4].x, dtsh[tok][k4*4+0], acc[tok]);
                acc[tok] = fmaf(wv[k4].y, dtsh[tok][k4*4+1], acc[tok]);
                acc[tok] = fmaf(wv[k4].z, dtsh[tok][k4*4+2], acc[tok]);
                acc[tok] = fmaf(wv[k4].w, dtsh[tok][k4*4+3], acc[tok]);
            }
        }
        #pragma unroll
        for (int tok = 0; tok < 4; ++tok)
            delta[(size_t)(blk*4 + tok)*DI + d] = softplusf(acc[tok]);
    }
}

// ------- causal depthwise conv (DC=4) + bias + SiLU -> split bf16 ----------
__global__ __launch_bounds__(256) void conv_silu_k(const float* __restrict__ xz,
                                                   const float* __restrict__ cw,
                                                   const float* __restrict__ cb,
                                                   bf16_t* __restrict__ xch,
                                                   bf16_t* __restrict__ xcl)
{
    int idx = blockIdx.x * 256 + threadIdx.x;
    int d4 = idx & (DI/4 - 1);
    int m  = idx >> 9;
    int l  = m & (L_ - 1);
    int d  = d4 * 4;

    float4 w0 = *(const float4*)(cw + (size_t)(d+0)*DC);
    float4 w1 = *(const float4*)(cw + (size_t)(d+1)*DC);
    float4 w2 = *(const float4*)(cw + (size_t)(d+2)*DC);
    float4 w3 = *(const float4*)(cw + (size_t)(d+3)*DC);
    float wr0[4] = {w0.x,w0.y,w0.z,w0.w};
    float wr1[4] = {w1.x,w1.y,w1.z,w1.w};
    float wr2[4] = {w2.x,w2.y,w2.z,w2.w};
    float wr3[4] = {w3.x,w3.y,w3.z,w3.w};
    float4 bias = *(const float4*)(cb + d);
    float a0 = bias.x, a1 = bias.y, a2 = bias.z, a3 = bias.w;

    #pragma unroll
    for (int j = 0; j < DC; ++j) {
        int tt = l - (DC-1) + j;
        if (tt < 0) continue;
        float4 xv = *(const float4*)(xz + (size_t)(m - l + tt)*(2*DI) + d);
        a0 = fmaf(wr0[j], xv.x, a0);
        a1 = fmaf(wr1[j], xv.y, a1);
        a2 = fmaf(wr2[j], xv.z, a2);
        a3 = fmaf(wr3[j], xv.w, a3);
    }
    float o[4] = { siluf(a0), siluf(a1), siluf(a2), siluf(a3) };
    bf16x4 hv, lv;
    #pragma unroll
    for (int j = 0; j < 4; ++j) { hl_t s = split2(o[j]); hv[j] = s.h; lv[j] = s.l; }
    *(bf16x4*)(xch + (size_t)m*DI + d) = hv;
    *(bf16x4*)(xcl + (size_t)m*DI + d) = lv;
}

// ---------------- chunked selective scan (NC=32 chunks of CL=32) -----------
// Phase 1: per-chunk partial state H[16] from h=0, plus S = sum(delta).
__global__ __launch_bounds__(256) void scan_p1(const float* __restrict__ delta,
                                               const bf16_t* __restrict__ xch,
                                               const bf16_t* __restrict__ xcl,
                                               const float* __restrict__ bc,
                                               const float* __restrict__ A_log,
                                               float* __restrict__ Sbuf,
                                               float* __restrict__ Hbuf)
{
    __shared__ float Bsh[CL][16];
    int t = threadIdx.x;
    int blk = blockIdx.x;                 // b*(NC*8) + c*8 + dblk
    int d = (blk & 7) * 256 + t;
    int c = (blk >> 3) & (NC - 1);
    int b = blk >> 8;
    int m0 = b * L_ + c * CL;

    for (int i = t; i < CL*16; i += 256)
        Bsh[i >> 4][i & 15] = bc[(size_t)(m0 + (i >> 4))*32 + (i & 15)];
    __syncthreads();

    float A[16], h[16];
    #pragma unroll
    for (int j = 0; j < 4; ++j) {
        float4 al = *(const float4*)(A_log + (size_t)d*DS + j*4);
        A[j*4+0] = -__expf(al.x); A[j*4+1] = -__expf(al.y);
        A[j*4+2] = -__expf(al.z); A[j*4+3] = -__expf(al.w);
    }
    #pragma unroll
    for (int n = 0; n < 16; ++n) h[n] = 0.f;
    float S = 0.f;

    #pragma unroll 4
    for (int tt = 0; tt < CL; ++tt) {
        int m = m0 + tt;
        float dv = delta[(size_t)m*DI + d];
        float xv = (float)xch[(size_t)m*DI + d] + (float)xcl[(size_t)m*DI + d];
        float dx = dv * xv;
        S += dv;
        #pragma unroll
        for (int n = 0; n < 16; ++n) {
            float dA = __expf(dv * A[n]);
            h[n] = fmaf(dA, h[n], Bsh[tt][n] * dx);
        }
    }

    Sbuf[(size_t)(b*NC + c)*DI + d] = S;
    size_t o = ((size_t)((b*NC + c)*DI) + d) * DS;
    #pragma unroll
    for (int j = 0; j < 4; ++j) {
        float4 hv;
        hv.x = h[j*4+0]; hv.y = h[j*4+1]; hv.z = h[j*4+2]; hv.w = h[j*4+3];
        *(float4*)(Hbuf + o + j*4) = hv;
    }
}

// Phase 3 (now includes the former p2): compute h0 by scanning the chunk
// summaries for chunks 0..c-1 (identical arithmetic order -> identical
// values), then replay chunk and emit g = (y + xc*D)*silu(z) as split bf16.
__global__ __launch_bounds__(256) void scan_p3(const float* __restrict__ delta,
                                               const float* __restrict__ xz,
                                               const bf16_t* __restrict__ xch,
                                               const bf16_t* __restrict__ xcl,
                                               const float* __restrict__ bc,
                                               const float* __restrict__ A_log,
                                               const float* __restrict__ Dp,
                                               const float* __restrict__ Sbuf,
                                               const float* __restrict__ Hbuf,
                                               bf16_t* __restrict__ gh,
                                               bf16_t* __restrict__ gl)
{
    __shared__ float Bsh[CL][16];
    __shared__ float Csh[CL][16];
    int t = threadIdx.x;
    int blk = blockIdx.x;
    int d = (blk & 7) * 256 + t;
    int c = (blk >> 3) & (NC - 1);
    int b = blk >> 8;
    int m0 = b * L_ + c * CL;

    for (int i = t; i < CL*16; i += 256) {
        int tt = i >> 4, n = i & 15;
        size_t ro = (size_t)(m0 + tt)*32;
        Bsh[tt][n] = bc[ro + n];
        Csh[tt][n] = bc[ro + 16 + n];
    }
    __syncthreads();

    float A[16], h[16];
    #pragma unroll
    for (int j = 0; j < 4; ++j) {
        float4 al = *(const float4*)(A_log + (size_t)d*DS + j*4);
        A[j*4+0] = -__expf(al.x); A[j*4+1] = -__expf(al.y);
        A[j*4+2] = -__expf(al.z); A[j*4+3] = -__expf(al.w);
    }
    // ---- h0 prefix over preceding chunks (was scan_p2) ----
    #pragma unroll
    for (int n = 0; n < 16; ++n) h[n] = 0.f;
    for (int j = 0; j < c; ++j) {
        size_t so = (size_t)(b*NC + j)*DI + d;
        float S = Sbuf[so];
        size_t o = so * DS;
        float Hj[16];
        #pragma unroll
        for (int q = 0; q < 4; ++q) {
            float4 hv = *(const float4*)(Hbuf + o + q*4);
            Hj[q*4+0] = hv.x; Hj[q*4+1] = hv.y; Hj[q*4+2] = hv.z; Hj[q*4+3] = hv.w;
        }
        #pragma unroll
        for (int n = 0; n < 16; ++n)
            h[n] = fmaf(__expf(A[n]*S), h[n], Hj[n]);
    }
    float Dreg = Dp[d];

    for (int t0 = 0; t0 < CL; t0 += 4) {
        float dv[4], xv[4], zv[4];
        #pragma unroll
        for (int q = 0; q < 4; ++q) {
            int m = m0 + t0 + q;
            dv[q] = delta[(size_t)m*DI + d];
            xv[q] = (float)xch[(size_t)m*DI + d] + (float)xcl[(size_t)m*DI + d];
            zv[q] = xz[(size_t)m*(2*DI) + DI + d];
        }
        #pragma unroll
        for (int q = 0; q < 4; ++q) {
            int tt = t0 + q, m = m0 + tt;
            float dx = dv[q] * xv[q];
            float y = 0.f;
            #pragma unroll
            for (int n = 0; n < 16; ++n) {
                float dA = __expf(dv[q] * A[n]);
                h[n] = fmaf(dA, h[n], Bsh[tt][n] * dx);
                y = fmaf(h[n], Csh[tt][n], y);
            }
            float gv = (y + xv[q]*Dreg) * siluf(zv[q]);
            hl_t s = split2(gv);
            gh[(size_t)m*DI + d] = s.h;
            gl[(size_t)m*DI + d] = s.l;
        }
    }
}

extern "C" void kernel_launch(void* const* d_in, const int* in_sizes, int n_in,
                              void* d_out, int out_size, void* d_ws, size_t ws_size,
                              hipStream_t stream)
{
    const float* x         = (const float*)d_in[0];
    const float* norm_w    = (const float*)d_in[1];
    const float* in_proj_w = (const float*)d_in[2];
    const float* conv_w    = (const float*)d_in[3];
    const float* conv_b    = (const float*)d_in[4];
    const float* x_proj_w  = (const float*)d_in[5];
    const float* dt_proj_w = (const float*)d_in[6];
    const float* dt_proj_b = (const float*)d_in[7];
    const float* A_log     = (const float*)d_in[8];
    const float* Dp        = (const float*)d_in[9];
    const float* out_proj_w= (const float*)d_in[10];
    float* out = (float*)d_out;

    char* p = (char*)d_ws;
    float*  xz    = (float*)p;  p += (size_t)NTOK*2*DI*4;    // 33.55 MB
    bf16_t* xch   = (bf16_t*)p; p += (size_t)NTOK*DI*2;      //  8.39 MB
    bf16_t* xcl   = (bf16_t*)p; p += (size_t)NTOK*DI*2;      //  8.39 MB
    float*  delta = (float*)p;  p += (size_t)NTOK*DI*4;      // 16.78 MB
    float*  bc    = (float*)p;  p += (size_t)NTOK*32*4;      //  0.26 MB
    float*  Hbuf  = (float*)p;  p += (size_t)B_*NC*DI*DS*4;  //  8.39 MB (also uh/ul, parts)
    char*   Wreg  = p;          p += (size_t)2*DI*DM*2*2;    // 16.78 MB (wih/wil -> gh/gl)
    bf16_t* woh   = (bf16_t*)p; p += (size_t)DM*DI*2;        //  4.19 MB (dedicated)
    bf16_t* wol   = (bf16_t*)p; p += (size_t)DM*DI*2;        //  4.19 MB (dedicated)
    float*  Sbuf  = (float*)p;  p += (size_t)B_*NC*DI*4;     //  0.52 MB (dedicated)
    bf16_t* wxh   = (bf16_t*)p; p += (size_t)128*DI*2;       //  0.52 MB
    bf16_t* wxl   = (bf16_t*)p; p += (size_t)128*DI*2;       //  0.52 MB
    // total ~102.5 MB

    // Hbuf region staged reuse: uh/ul (pre-in_proj) -> parts (x_proj partials)
    // -> H summaries (scan). Each lifetime ends before the next begins.
    bf16_t* uh  = (bf16_t*)Hbuf;
    bf16_t* ul  = uh + (size_t)NTOK*DM;
    float*  parts = Hbuf;
    // Wreg: wih/wil (in_proj weights, dead after step 2) -> gh/gl (step 6+)
    bf16_t* wih = (bf16_t*)Wreg;
    bf16_t* wil = wih + (size_t)2*DI*DM;
    bf16_t* gh  = (bf16_t*)Wreg;
    bf16_t* gl  = gh + (size_t)NTOK*DI;

    // 1. RMSNorm + all weight splits (one launch)
    rms_split_all<<<NTOK + SPLIT_IN_BLKS + SPLIT_X_BLKS + SPLIT_O_BLKS, 256, 0, stream>>>(
        x, norm_w, uh, ul, in_proj_w, wih, wil, x_proj_w, wxh, wxl,
        out_proj_w, woh, wol);

    // 2. in_proj (MFMA, XCD-swizzled): xz[2048,4096] = u @ in_proj_w^T
    gemm_mfma<128,0,false><<<dim3((2*DI)/128, NTOK/128), 256, 0, stream>>>(
        uh, ul, wih, wil, xz, 2*DI, nullptr, NTOK, 2*DI, DM, 0);

    // 3. causal depthwise conv + SiLU -> split bf16 xc
    conv_silu_k<<<(NTOK*(DI/4))/256, 256, 0, stream>>>(xz, conv_w, conv_b, xch, xcl);

    // 4. x_proj (MFMA, split-K over K=2048): parts[8][2048][128]
    gemm_mfma<128,0,true><<<dim3(SPLITS, NTOK/128), 256, 0, stream>>>(
        xch, xcl, wxh, wxl, parts, 128, nullptr, NTOK, 128, DI, DI/SPLITS);

    // 5. reduce partials + fused dt_proj matvec (fp32), 512 blocks (2/CU)
    dt_fuse<<<NTOK/4, 256, 0, stream>>>(parts, bc, dt_proj_w, dt_proj_b, delta);

    // 6. chunked selective scan (p2 folded into p3)
    scan_p1<<<B_*NC*(DI/256), 256, 0, stream>>>(delta, xch, xcl, bc, A_log, Sbuf, Hbuf);
    scan_p3<<<B_*NC*(DI/256), 256, 0, stream>>>(delta, xz, xch, xcl, bc, A_log, Dp,
                                                Sbuf, Hbuf, gh, gl);

    // 7. out_proj (MFMA, XCD-swizzled) + residual: out = g @ out_proj_w^T + x
    gemm_mfma<64,2,false><<<dim3(DM/64, NTOK/128), 256, 0, stream>>>(
        gh, gl, woh, wol, out, DM, x, NTOK, DM, DI, 0);
}

// Round 11
// 320.619 us; speedup vs baseline: 1.0404x; 1.0404x over previous
//
#include <hip/hip_runtime.h>
#include <math.h>

#define B_   2
#define L_   1024
#define DM   1024
#define DS   16
#define DC   4
#define DI   2048          // E*DM
#define DR   64            // DM/16
#define NTOK (B_*L_)       // 2048
#define EPSF 1e-5f
#define NC   32            // scan chunks
#define CL   (L_/NC)       // 32 steps per chunk
#define SPLITS 8           // x_proj K-splits

typedef __bf16 bf16_t;
typedef bf16_t bf16x4 __attribute__((ext_vector_type(4)));
typedef bf16_t bf16x8 __attribute__((ext_vector_type(8)));
typedef float  f32x4  __attribute__((ext_vector_type(4)));

__device__ __forceinline__ float siluf(float x){ return x / (1.f + __expf(-x)); }
__device__ __forceinline__ float softplusf(float x){ return (x > 20.f) ? x : log1pf(__expf(x)); }

__device__ __forceinline__ void gload_lds16(const void* g, void* l) {
    __builtin_amdgcn_global_load_lds(
        (const __attribute__((address_space(1))) void*)g,
        (__attribute__((address_space(3))) void*)l, 16, 0, 0);
}

// value-returning split (vector elements can't bind to references)
struct hl_t { bf16_t h, l; };
__device__ __forceinline__ hl_t split2(float v) {
    hl_t r;
    r.h = (bf16_t)v;
    r.l = (bf16_t)(v - (float)r.h);
    return r;
}

// ==== launch 1: RMSNorm (blocks 0..2047) + ALL weight splits (incl out_w) ===
#define SPLIT_IN_BLKS  ((2*DI*DM/4)/256)   // 8192
#define SPLIT_X_BLKS   ((128*DI/4)/256)    // 256
#define SPLIT_O_BLKS   ((DM*DI/4)/256)     // 2048
__global__ __launch_bounds__(256) void rms_split_all(
    const float* __restrict__ x, const float* __restrict__ w,
    bf16_t* __restrict__ uh, bf16_t* __restrict__ ul,
    const float* __restrict__ in_w, bf16_t* __restrict__ wih, bf16_t* __restrict__ wil,
    const float* __restrict__ x_w,  bf16_t* __restrict__ wxh,  bf16_t* __restrict__ wxl,
    const float* __restrict__ out_w, bf16_t* __restrict__ woh, bf16_t* __restrict__ wol)
{
    __shared__ float sred[4];
    int blk = blockIdx.x;
    int t = threadIdx.x;

    if (blk < NTOK) {                       // ---- RMSNorm row ----
        int row = blk;
        float4 v = ((const float4*)(x + (size_t)row*DM))[t];
        float ss = v.x*v.x + v.y*v.y + v.z*v.z + v.w*v.w;
        #pragma unroll
        for (int off = 32; off > 0; off >>= 1) ss += __shfl_xor(ss, off, 64);
        if ((t & 63) == 0) sred[t >> 6] = ss;
        __syncthreads();
        ss = sred[0] + sred[1] + sred[2] + sred[3];
        float rs = rsqrtf(ss * (1.f/(float)DM) + EPSF);
        float4 wv = ((const float4*)w)[t];
        float o[4];
        o[0] = v.x*rs*wv.x; o[1] = v.y*rs*wv.y; o[2] = v.z*rs*wv.z; o[3] = v.w*rs*wv.w;
        bf16x4 hv, lv;
        #pragma unroll
        for (int j = 0; j < 4; ++j) { hl_t s = split2(o[j]); hv[j] = s.h; lv[j] = s.l; }
        *(bf16x4*)(uh + (size_t)row*DM + t*4) = hv;
        *(bf16x4*)(ul + (size_t)row*DM + t*4) = lv;
        return;
    }
    blk -= NTOK;
    if (blk < SPLIT_IN_BLKS) {              // ---- in_proj_w ----
        int i = blk * 256 + t;
        float4 v = ((const float4*)in_w)[i];
        float o[4] = {v.x, v.y, v.z, v.w};
        bf16x4 hv, lv;
        #pragma unroll
        for (int j = 0; j < 4; ++j) { hl_t s = split2(o[j]); hv[j] = s.h; lv[j] = s.l; }
        ((bf16x4*)wih)[i] = hv;
        ((bf16x4*)wil)[i] = lv;
        return;
    }
    blk -= SPLIT_IN_BLKS;
    if (blk < SPLIT_X_BLKS) {               // ---- x_proj_w padded 96->128 ----
        int i = blk * 256 + t;              // over 128*DI/4
        int row = i >> 9;                   // DI/4 = 512 float4 per row
        bf16x4 hv, lv;
        if (row < 96) {
            float4 v = ((const float4*)x_w)[i];
            float o[4] = {v.x, v.y, v.z, v.w};
            #pragma unroll
            for (int j = 0; j < 4; ++j) { hl_t s = split2(o[j]); hv[j] = s.h; lv[j] = s.l; }
        } else {
            #pragma unroll
            for (int j = 0; j < 4; ++j) { hv[j] = (bf16_t)0.f; lv[j] = (bf16_t)0.f; }
        }
        ((bf16x4*)wxh)[i] = hv;
        ((bf16x4*)wxl)[i] = lv;
        return;
    }
    blk -= SPLIT_X_BLKS;
    {                                       // ---- out_proj_w ----
        int i = blk * 256 + t;              // over DM*DI/4
        float4 v = ((const float4*)out_w)[i];
        float o[4] = {v.x, v.y, v.z, v.w};
        bf16x4 hv, lv;
        #pragma unroll
        for (int j = 0; j < 4; ++j) { hl_t s = split2(o[j]); hv[j] = s.h; lv[j] = s.l; }
        ((bf16x4*)woh)[i] = hv;
        ((bf16x4*)wol)[i] = lv;
    }
}

// ---------------- split-bf16 MFMA NT GEMM, 2-phase double-buffered ---------
// Round-4 structure (no LDS swizzle — A/B'd at −2x on dt_proj, r7) PLUS
// XCD-aware block swizzle (T1): each XCD owns a contiguous n-chunk and walks
// all m-tiles, so its B-panels stay in its private L2 while A streams via L3.
// REQUIRES (non-SK): gridDim.x % 8 == 0 and gridDim.y == 16.
template<int BN, int EPI, bool SK>
__global__ __launch_bounds__(256) void gemm_mfma(
    const bf16_t* __restrict__ Ah, const bf16_t* __restrict__ Al,
    const bf16_t* __restrict__ Bh, const bf16_t* __restrict__ Bl,
    float* __restrict__ C, int ldc,
    const float* __restrict__ res,
    int M, int N, int K, int kspl)
{
    constexpr int NJ   = BN / 32;
    constexpr int WN   = BN / 2;
    constexpr int ACH  = 8;
    constexpr int BCH  = BN / 16;
    constexpr int NCH  = 2*ACH + 2*BCH;
    constexpr int PERW = NCH / 4;
    constexpr int AOFF_L = 128*32;
    constexpr int BOFF_H = 2*128*32;
    constexpr int BOFF_L = 2*128*32 + BN*32;
    constexpr int BUFSZ  = 2*128*32 + 2*BN*32;

    __shared__ bf16_t lds[2*BUFSZ];

    int t = threadIdx.x;
    int w = t >> 6, lane = t & 63;
    int wr = w >> 1, wc = w & 1;

    int bx, by;
    if (!SK) {                      // XCD swizzle (bijective: gx%8==0, gy==16)
        int bid = blockIdx.y * gridDim.x + blockIdx.x;
        int xcd = bid & 7;
        int i   = bid >> 3;
        bx = xcd * (int)(gridDim.x >> 3) + (i >> 4);
        by = i & 15;
    } else { bx = blockIdx.x; by = blockIdx.y; }

    int m0 = by * 128;
    int n0 = SK ? 0 : bx * BN;
    int k0beg = SK ? bx * kspl : 0;
    int nst = (SK ? kspl : K) >> 5;
    float* Cp = C;
    if (SK) Cp += (size_t)bx * M * BN;

    f32x4 acc[4][NJ];
    #pragma unroll
    for (int i = 0; i < 4; ++i)
        #pragma unroll
        for (int j = 0; j < NJ; ++j)
            acc[i][j] = (f32x4){0.f, 0.f, 0.f, 0.f};

    int lrow = lane >> 2;          // row within 16-row chunk
    int lcol = (lane & 3) * 8;     // k element offset
    int ar   = wr*64 + (lane & 15);
    int br   = wc*WN + (lane & 15);
    int koff = (lane >> 4) * 8;

    auto STAGE = [&](int buf, int k0) {
        int base = buf ? BUFSZ : 0;
        #pragma unroll
        for (int q = 0; q < PERW; ++q) {
            int ch = w * PERW + q;
            const bf16_t* g; int le;
            if (ch < ACH) {
                int cc = ch;
                g  = Ah + (size_t)(m0 + cc*16 + lrow)*K + k0 + lcol;
                le = cc*512 + lane*8;
            } else if (ch < 2*ACH) {
                int cc = ch - ACH;
                g  = Al + (size_t)(m0 + cc*16 + lrow)*K + k0 + lcol;
                le = AOFF_L + cc*512 + lane*8;
            } else if (ch < 2*ACH + BCH) {
                int cc = ch - 2*ACH;
                g  = Bh + (size_t)(n0 + cc*16 + lrow)*K + k0 + lcol;
                le = BOFF_H + cc*512 + lane*8;
            } else {
                int cc = ch - 2*ACH - BCH;
                g  = Bl + (size_t)(n0 + cc*16 + lrow)*K + k0 + lcol;
                le = BOFF_L + cc*512 + lane*8;
            }
            gload_lds16(g, &lds[base + le]);
        }
    };

    STAGE(0, k0beg);
    __syncthreads();
    int cur = 0;
    for (int s = 0; s < nst; ++s) {
        int k0 = k0beg + (s << 5);
        if (s + 1 < nst) STAGE(cur ^ 1, k0 + 32);
        int base = cur ? BUFSZ : 0;

        bf16x8 ah[4], al4[4], bh[NJ], bl4[NJ];
        #pragma unroll
        for (int i = 0; i < 4; ++i) {
            ah[i]  = *(const bf16x8*)&lds[base + (ar + i*16)*32 + koff];
            al4[i] = *(const bf16x8*)&lds[base + AOFF_L + (ar + i*16)*32 + koff];
        }
        #pragma unroll
        for (int j = 0; j < NJ; ++j) {
            bh[j]  = *(const bf16x8*)&lds[base + BOFF_H + (br + j*16)*32 + koff];
            bl4[j] = *(const bf16x8*)&lds[base + BOFF_L + (br + j*16)*32 + koff];
        }
        #pragma unroll
        for (int i = 0; i < 4; ++i)
            #pragma unroll
            for (int j = 0; j < NJ; ++j) {
                acc[i][j] = __builtin_amdgcn_mfma_f32_16x16x32_bf16(ah[i],  bh[j],  acc[i][j], 0, 0, 0);
                acc[i][j] = __builtin_amdgcn_mfma_f32_16x16x32_bf16(al4[i], bh[j],  acc[i][j], 0, 0, 0);
                acc[i][j] = __builtin_amdgcn_mfma_f32_16x16x32_bf16(ah[i],  bl4[j], acc[i][j], 0, 0, 0);
            }
        __syncthreads();
        cur ^= 1;
    }

    // epilogue: C/D layout col=lane&15, row=(lane>>4)*4+reg  [m89-verified]
    int rb = m0 + wr*64 + (lane >> 4)*4;
    int cb = n0 + wc*WN + (lane & 15);
    #pragma unroll
    for (int i = 0; i < 4; ++i)
        #pragma unroll
        for (int j = 0; j < NJ; ++j) {
            int col = cb + j*16;
            #pragma unroll
            for (int r = 0; r < 4; ++r) {
                int row = rb + i*16 + r;
                float v = acc[i][j][r];
                if (EPI == 2) v += res[(size_t)row*ldc + col];
                Cp[(size_t)row*ldc + col] = v;
            }
        }
}

// ==== launch 5: x_proj reduce + fused dt_proj matvec =======================
// 1024 blocks (4/CU): blk>>1 = 4-token group, blk&1 = d-half (0..1023 or
// 1024..2047). Phase A (threads 0..127): reduce split-K partials for the
// 4 tokens into LDS dt[4][64]; bc written by half-0 blocks only. Phase B:
// each thread streams 4 d-cols of dt_w (partial unroll 4 -> ~48 VGPR, loads
// pipelined against FMAs), softplus, coalesced fp32 stores.
__global__ __launch_bounds__(256) void dt_fuse(
    const float* __restrict__ parts,
    float* __restrict__ bc,
    const float* __restrict__ dt_w,     // [DI, DR] fp32
    const float* __restrict__ dt_b,     // [DI]
    float* __restrict__ delta)          // [NTOK, DI]
{
    __shared__ float dtsh[4][DR];       // 1 KB
    int blk = blockIdx.x;               // 0..1023
    int hf  = blk & 1;                  // d-half
    int tb  = blk >> 1;                 // token group 0..511
    int t = threadIdx.x;
    if (t < 128) {
        int token = t >> 5;             // 0..3
        int c = (t & 31) * 4;           // 0..124
        int m = tb*4 + token;
        float4 s = {0.f, 0.f, 0.f, 0.f};
        #pragma unroll
        for (int sp = 0; sp < SPLITS; ++sp) {
            float4 v = *(const float4*)(parts + ((size_t)sp*NTOK + m)*128 + c);
            s.x += v.x; s.y += v.y; s.z += v.z; s.w += v.w;
        }
        if (c < 64) {
            *(float4*)&dtsh[token][c] = s;
        } else if (c < 96 && hf == 0) {
            *(float4*)(bc + (size_t)m*32 + (c - 64)) = s;
        }
    }
    __syncthreads();
    // phase B: 4 d-columns per thread (this half), 4 tokens, streamed weights
    for (int dd = 0; dd < 4; ++dd) {
        int d = hf*1024 + dd*256 + t;
        const float4* wp = (const float4*)(dt_w + (size_t)d*DR);
        float bb = dt_b[d];
        float a0 = bb, a1 = bb, a2 = bb, a3 = bb;
        #pragma unroll 4
        for (int k4 = 0; k4 < 16; ++k4) {
            float4 wv = wp[k4];
            a0 = fmaf(wv.x, dtsh[0][k4*4+0], a0);
            a1 = fmaf(wv.x, dtsh[1][k4*4+0], a1);
            a2 = fmaf(wv.x, dtsh[2][k4*4+0], a2);
            a3 = fmaf(wv.x, dtsh[3][k4*4+0], a3);
            a0 = fmaf(wv.y, dtsh[0][k4*4+1], a0);
            a1 = fmaf(wv.y, dtsh[1][k4*4+1], a1);
            a2 = fmaf(wv.y, dtsh[2][k4*4+1], a2);
            a3 = fmaf(wv.y, dtsh[3][k4*4+1], a3);
            a0 = fmaf(wv.z, dtsh[0][k4*4+2], a0);
            a1 = fmaf(wv.z, dtsh[1][k4*4+2], a1);
            a2 = fmaf(wv.z, dtsh[2][k4*4+2], a2);
            a3 = fmaf(wv.z, dtsh[3][k4*4+2], a3);
            a0 = fmaf(wv.w, dtsh[0][k4*4+3], a0);
            a1 = fmaf(wv.w, dtsh[1][k4*4+3], a1);
            a2 = fmaf(wv.w, dtsh[2][k4*4+3], a2);
            a3 = fmaf(wv.w, dtsh[3][k4*4+3], a3);
        }
        delta[(size_t)(tb*4 + 0)*DI + d] = softplusf(a0);
        delta[(size_t)(tb*4 + 1)*DI + d] = softplusf(a1);
        delta[(size_t)(tb*4 + 2)*DI + d] = softplusf(a2);
        delta[(size_t)(tb*4 + 3)*DI + d] = softplusf(a3);
    }
}

// ------- causal depthwise conv (DC=4) + bias + SiLU -> split bf16 ----------
__global__ __launch_bounds__(256) void conv_silu_k(const float* __restrict__ xz,
                                                   const float* __restrict__ cw,
                                                   const float* __restrict__ cb,
                                                   bf16_t* __restrict__ xch,
                                                   bf16_t* __restrict__ xcl)
{
    int idx = blockIdx.x * 256 + threadIdx.x;
    int d4 = idx & (DI/4 - 1);
    int m  = idx >> 9;
    int l  = m & (L_ - 1);
    int d  = d4 * 4;

    float4 w0 = *(const float4*)(cw + (size_t)(d+0)*DC);
    float4 w1 = *(const float4*)(cw + (size_t)(d+1)*DC);
    float4 w2 = *(const float4*)(cw + (size_t)(d+2)*DC);
    float4 w3 = *(const float4*)(cw + (size_t)(d+3)*DC);
    float wr0[4] = {w0.x,w0.y,w0.z,w0.w};
    float wr1[4] = {w1.x,w1.y,w1.z,w1.w};
    float wr2[4] = {w2.x,w2.y,w2.z,w2.w};
    float wr3[4] = {w3.x,w3.y,w3.z,w3.w};
    float4 bias = *(const float4*)(cb + d);
    float a0 = bias.x, a1 = bias.y, a2 = bias.z, a3 = bias.w;

    #pragma unroll
    for (int j = 0; j < DC; ++j) {
        int tt = l - (DC-1) + j;
        if (tt < 0) continue;
        float4 xv = *(const float4*)(xz + (size_t)(m - l + tt)*(2*DI) + d);
        a0 = fmaf(wr0[j], xv.x, a0);
        a1 = fmaf(wr1[j], xv.y, a1);
        a2 = fmaf(wr2[j], xv.z, a2);
        a3 = fmaf(wr3[j], xv.w, a3);
    }
    float o[4] = { siluf(a0), siluf(a1), siluf(a2), siluf(a3) };
    bf16x4 hv, lv;
    #pragma unroll
    for (int j = 0; j < 4; ++j) { hl_t s = split2(o[j]); hv[j] = s.h; lv[j] = s.l; }
    *(bf16x4*)(xch + (size_t)m*DI + d) = hv;
    *(bf16x4*)(xcl + (size_t)m*DI + d) = lv;
}

// ---------------- chunked selective scan (NC=32 chunks of CL=32) -----------
// Phase 1: per-chunk partial state H[16] from h=0, plus S = sum(delta).
__global__ __launch_bounds__(256) void scan_p1(const float* __restrict__ delta,
                                               const bf16_t* __restrict__ xch,
                                               const bf16_t* __restrict__ xcl,
                                               const float* __restrict__ bc,
                                               const float* __restrict__ A_log,
                                               float* __restrict__ Sbuf,
                                               float* __restrict__ Hbuf)
{
    __shared__ float Bsh[CL][16];
    int t = threadIdx.x;
    int blk = blockIdx.x;                 // b*(NC*8) + c*8 + dblk
    int d = (blk & 7) * 256 + t;
    int c = (blk >> 3) & (NC - 1);
    int b = blk >> 8;
    int m0 = b * L_ + c * CL;

    for (int i = t; i < CL*16; i += 256)
        Bsh[i >> 4][i & 15] = bc[(size_t)(m0 + (i >> 4))*32 + (i & 15)];
    __syncthreads();

    float A[16], h[16];
    #pragma unroll
    for (int j = 0; j < 4; ++j) {
        float4 al = *(const float4*)(A_log + (size_t)d*DS + j*4);
        A[j*4+0] = -__expf(al.x); A[j*4+1] = -__expf(al.y);
        A[j*4+2] = -__expf(al.z); A[j*4+3] = -__expf(al.w);
    }
    #pragma unroll
    for (int n = 0; n < 16; ++n) h[n] = 0.f;
    float S = 0.f;

    #pragma unroll 4
    for (int tt = 0; tt < CL; ++tt) {
        int m = m0 + tt;
        float dv = delta[(size_t)m*DI + d];
        float xv = (float)xch[(size_t)m*DI + d] + (float)xcl[(size_t)m*DI + d];
        float dx = dv * xv;
        S += dv;
        #pragma unroll
        for (int n = 0; n < 16; ++n) {
            float dA = __expf(dv * A[n]);
            h[n] = fmaf(dA, h[n], Bsh[tt][n] * dx);
        }
    }

    Sbuf[(size_t)(b*NC + c)*DI + d] = S;
    size_t o = ((size_t)((b*NC + c)*DI) + d) * DS;
    #pragma unroll
    for (int j = 0; j < 4; ++j) {
        float4 hv;
        hv.x = h[j*4+0]; hv.y = h[j*4+1]; hv.z = h[j*4+2]; hv.w = h[j*4+3];
        *(float4*)(Hbuf + o + j*4) = hv;
    }
}

// Phase 3 (includes the former p2): compute h0 by scanning the chunk
// summaries for chunks 0..c-1 (identical arithmetic order -> identical
// values), then replay chunk and emit g = (y + xc*D)*silu(z) as split bf16.
__global__ __launch_bounds__(256) void scan_p3(const float* __restrict__ delta,
                                               const float* __restrict__ xz,
                                               const bf16_t* __restrict__ xch,
                                               const bf16_t* __restrict__ xcl,
                                               const float* __restrict__ bc,
                                               const float* __restrict__ A_log,
                                               const float* __restrict__ Dp,
                                               const float* __restrict__ Sbuf,
                                               const float* __restrict__ Hbuf,
                                               bf16_t* __restrict__ gh,
                                               bf16_t* __restrict__ gl)
{
    __shared__ float Bsh[CL][16];
    __shared__ float Csh[CL][16];
    int t = threadIdx.x;
    int blk = blockIdx.x;
    int d = (blk & 7) * 256 + t;
    int c = (blk >> 3) & (NC - 1);
    int b = blk >> 8;
    int m0 = b * L_ + c * CL;

    for (int i = t; i < CL*16; i += 256) {
        int tt = i >> 4, n = i & 15;
        size_t ro = (size_t)(m0 + tt)*32;
        Bsh[tt][n] = bc[ro + n];
        Csh[tt][n] = bc[ro + 16 + n];
    }
    __syncthreads();

    float A[16], h[16];
    #pragma unroll
    for (int j = 0; j < 4; ++j) {
        float4 al = *(const float4*)(A_log + (size_t)d*DS + j*4);
        A[j*4+0] = -__expf(al.x); A[j*4+1] = -__expf(al.y);
        A[j*4+2] = -__expf(al.z); A[j*4+3] = -__expf(al.w);
    }
    // ---- h0 prefix over preceding chunks (was scan_p2) ----
    #pragma unroll
    for (int n = 0; n < 16; ++n) h[n] = 0.f;
    for (int j = 0; j < c; ++j) {
        size_t so = (size_t)(b*NC + j)*DI + d;
        float S = Sbuf[so];
        size_t o = so * DS;
        float Hj[16];
        #pragma unroll
        for (int q = 0; q < 4; ++q) {
            float4 hv = *(const float4*)(Hbuf + o + q*4);
            Hj[q*4+0] = hv.x; Hj[q*4+1] = hv.y; Hj[q*4+2] = hv.z; Hj[q*4+3] = hv.w;
        }
        #pragma unroll
        for (int n = 0; n < 16; ++n)
            h[n] = fmaf(__expf(A[n]*S), h[n], Hj[n]);
    }
    float Dreg = Dp[d];

    for (int t0 = 0; t0 < CL; t0 += 4) {
        float dv[4], xv[4], zv[4];
        #pragma unroll
        for (int q = 0; q < 4; ++q) {
            int m = m0 + t0 + q;
            dv[q] = delta[(size_t)m*DI + d];
            xv[q] = (float)xch[(size_t)m*DI + d] + (float)xcl[(size_t)m*DI + d];
            zv[q] = xz[(size_t)m*(2*DI) + DI + d];
        }
        #pragma unroll
        for (int q = 0; q < 4; ++q) {
            int tt = t0 + q, m = m0 + tt;
            float dx = dv[q] * xv[q];
            float y = 0.f;
            #pragma unroll
            for (int n = 0; n < 16; ++n) {
                float dA = __expf(dv[q] * A[n]);
                h[n] = fmaf(dA, h[n], Bsh[tt][n] * dx);
                y = fmaf(h[n], Csh[tt][n], y);
            }
            float gv = (y + xv[q]*Dreg) * siluf(zv[q]);
            hl_t s = split2(gv);
            gh[(size_t)m*DI + d] = s.h;
            gl[(size_t)m*DI + d] = s.l;
        }
    }
}

extern "C" void kernel_launch(void* const* d_in, const int* in_sizes, int n_in,
                              void* d_out, int out_size, void* d_ws, size_t ws_size,
                              hipStream_t stream)
{
    const float* x         = (const float*)d_in[0];
    const float* norm_w    = (const float*)d_in[1];
    const float* in_proj_w = (const float*)d_in[2];
    const float* conv_w    = (const float*)d_in[3];
    const float* conv_b    = (const float*)d_in[4];
    const float* x_proj_w  = (const float*)d_in[5];
    const float* dt_proj_w = (const float*)d_in[6];
    const float* dt_proj_b = (const float*)d_in[7];
    const float* A_log     = (const float*)d_in[8];
    const float* Dp        = (const float*)d_in[9];
    const float* out_proj_w= (const float*)d_in[10];
    float* out = (float*)d_out;

    char* p = (char*)d_ws;
    float*  xz    = (float*)p;  p += (size_t)NTOK*2*DI*4;    // 33.55 MB
    bf16_t* xch   = (bf16_t*)p; p += (size_t)NTOK*DI*2;      //  8.39 MB
    bf16_t* xcl   = (bf16_t*)p; p += (size_t)NTOK*DI*2;      //  8.39 MB
    float*  delta = (float*)p;  p += (size_t)NTOK*DI*4;      // 16.78 MB
    float*  bc    = (float*)p;  p += (size_t)NTOK*32*4;      //  0.26 MB
    float*  Hbuf  = (float*)p;  p += (size_t)B_*NC*DI*DS*4;  //  8.39 MB (also uh/ul, parts)
    char*   Wreg  = p;          p += (size_t)2*DI*DM*2*2;    // 16.78 MB (wih/wil -> gh/gl)
    bf16_t* woh   = (bf16_t*)p; p += (size_t)DM*DI*2;        //  4.19 MB (dedicated)
    bf16_t* wol   = (bf16_t*)p; p += (size_t)DM*DI*2;        //  4.19 MB (dedicated)
    float*  Sbuf  = (float*)p;  p += (size_t)B_*NC*DI*4;     //  0.52 MB (dedicated)
    bf16_t* wxh   = (bf16_t*)p; p += (size_t)128*DI*2;       //  0.52 MB
    bf16_t* wxl   = (bf16_t*)p; p += (size_t)128*DI*2;       //  0.52 MB
    // total ~102.5 MB

    // Hbuf region staged reuse: uh/ul (pre-in_proj) -> parts (x_proj partials)
    // -> H summaries (scan). Each lifetime ends before the next begins.
    bf16_t* uh  = (bf16_t*)Hbuf;
    bf16_t* ul  = uh + (size_t)NTOK*DM;
    float*  parts = Hbuf;
    // Wreg: wih/wil (in_proj weights, dead after step 2) -> gh/gl (step 6+)
    bf16_t* wih = (bf16_t*)Wreg;
    bf16_t* wil = wih + (size_t)2*DI*DM;
    bf16_t* gh  = (bf16_t*)Wreg;
    bf16_t* gl  = gh + (size_t)NTOK*DI;

    // 1. RMSNorm + all weight splits (one launch)
    rms_split_all<<<NTOK + SPLIT_IN_BLKS + SPLIT_X_BLKS + SPLIT_O_BLKS, 256, 0, stream>>>(
        x, norm_w, uh, ul, in_proj_w, wih, wil, x_proj_w, wxh, wxl,
        out_proj_w, woh, wol);

    // 2. in_proj (MFMA, XCD-swizzled): xz[2048,4096] = u @ in_proj_w^T
    gemm_mfma<128,0,false><<<dim3((2*DI)/128, NTOK/128), 256, 0, stream>>>(
        uh, ul, wih, wil, xz, 2*DI, nullptr, NTOK, 2*DI, DM, 0);

    // 3. causal depthwise conv + SiLU -> split bf16 xc
    conv_silu_k<<<(NTOK*(DI/4))/256, 256, 0, stream>>>(xz, conv_w, conv_b, xch, xcl);

    // 4. x_proj (MFMA, split-K over K=2048): parts[8][2048][128]
    gemm_mfma<128,0,true><<<dim3(SPLITS, NTOK/128), 256, 0, stream>>>(
        xch, xcl, wxh, wxl, parts, 128, nullptr, NTOK, 128, DI, DI/SPLITS);

    // 5. reduce partials + fused dt_proj matvec (fp32), 1024 blocks (4/CU)
    dt_fuse<<<(NTOK/4)*2, 256, 0, stream>>>(parts, bc, dt_proj_w, dt_proj_b, delta);

    // 6. chunked selective scan (p2 folded into p3)
    scan_p1<<<B_*NC*(DI/256), 256, 0, stream>>>(delta, xch, xcl, bc, A_log, Sbuf, Hbuf);
    scan_p3<<<B_*NC*(DI/256), 256, 0, stream>>>(delta, xz, xch, xcl, bc, A_log, Dp,
                                                Sbuf, Hbuf, gh, gl);

    // 7. out_proj (MFMA, XCD-swizzled) + residual: out = g @ out_proj_w^T + x
    gemm_mfma<64,2,false><<<dim3(DM/64, NTOK/128), 256, 0, stream>>>(
        gh, gl, woh, wol, out, DM, x, NTOK, DM, DI, 0);
}

// Round 12
// 292.176 us; speedup vs baseline: 1.1417x; 1.0973x over previous
//
#include <hip/hip_runtime.h>
#include <math.h>

#define B_   2
#define L_   1024
#define DM   1024
#define DS   16
#define DC   4
#define DI   2048          // E*DM
#define DR   64            // DM/16
#define NTOK (B_*L_)       // 2048
#define EPSF 1e-5f
#define NC   32            // scan chunks
#define CL   (L_/NC)       // 32 steps per chunk
#define SPLITS 8           // x_proj K-splits

typedef __bf16 bf16_t;
typedef bf16_t bf16x4 __attribute__((ext_vector_type(4)));
typedef bf16_t bf16x8 __attribute__((ext_vector_type(8)));
typedef float  f32x4  __attribute__((ext_vector_type(4)));

__device__ __forceinline__ float siluf(float x){ return x / (1.f + __expf(-x)); }
__device__ __forceinline__ float softplusf(float x){ return (x > 20.f) ? x : log1pf(__expf(x)); }

__device__ __forceinline__ void gload_lds16(const void* g, void* l) {
    __builtin_amdgcn_global_load_lds(
        (const __attribute__((address_space(1))) void*)g,
        (__attribute__((address_space(3))) void*)l, 16, 0, 0);
}

// value-returning split (vector elements can't bind to references)
struct hl_t { bf16_t h, l; };
__device__ __forceinline__ hl_t split2(float v) {
    hl_t r;
    r.h = (bf16_t)v;
    r.l = (bf16_t)(v - (float)r.h);
    return r;
}

// ==== launch 1: RMSNorm (blocks 0..2047) + weight hi-casts ==================
// Weights only need the hi word (B-side of every GEMM, sigma~0.02: the
// dropped a*b_lo term is ~2^-9 relative -> ~1e-3 abs on xz, well under tol).
#define SPLIT_IN_BLKS  ((2*DI*DM/4)/256)   // 8192
#define SPLIT_X_BLKS   ((128*DI/4)/256)    // 256
#define SPLIT_O_BLKS   ((DM*DI/4)/256)     // 2048
__global__ __launch_bounds__(256) void rms_split_all(
    const float* __restrict__ x, const float* __restrict__ w,
    bf16_t* __restrict__ uh, bf16_t* __restrict__ ul,
    const float* __restrict__ in_w, bf16_t* __restrict__ wih,
    const float* __restrict__ x_w,  bf16_t* __restrict__ wxh,
    const float* __restrict__ out_w, bf16_t* __restrict__ woh)
{
    __shared__ float sred[4];
    int blk = blockIdx.x;
    int t = threadIdx.x;

    if (blk < NTOK) {                       // ---- RMSNorm row (A-side: split) --
        int row = blk;
        float4 v = ((const float4*)(x + (size_t)row*DM))[t];
        float ss = v.x*v.x + v.y*v.y + v.z*v.z + v.w*v.w;
        #pragma unroll
        for (int off = 32; off > 0; off >>= 1) ss += __shfl_xor(ss, off, 64);
        if ((t & 63) == 0) sred[t >> 6] = ss;
        __syncthreads();
        ss = sred[0] + sred[1] + sred[2] + sred[3];
        float rs = rsqrtf(ss * (1.f/(float)DM) + EPSF);
        float4 wv = ((const float4*)w)[t];
        float o[4];
        o[0] = v.x*rs*wv.x; o[1] = v.y*rs*wv.y; o[2] = v.z*rs*wv.z; o[3] = v.w*rs*wv.w;
        bf16x4 hv, lv;
        #pragma unroll
        for (int j = 0; j < 4; ++j) { hl_t s = split2(o[j]); hv[j] = s.h; lv[j] = s.l; }
        *(bf16x4*)(uh + (size_t)row*DM + t*4) = hv;
        *(bf16x4*)(ul + (size_t)row*DM + t*4) = lv;
        return;
    }
    blk -= NTOK;
    if (blk < SPLIT_IN_BLKS) {              // ---- in_proj_w hi ----
        int i = blk * 256 + t;
        float4 v = ((const float4*)in_w)[i];
        bf16x4 hv;
        hv[0]=(bf16_t)v.x; hv[1]=(bf16_t)v.y; hv[2]=(bf16_t)v.z; hv[3]=(bf16_t)v.w;
        ((bf16x4*)wih)[i] = hv;
        return;
    }
    blk -= SPLIT_IN_BLKS;
    if (blk < SPLIT_X_BLKS) {               // ---- x_proj_w hi, padded 96->128 --
        int i = blk * 256 + t;              // over 128*DI/4
        int row = i >> 9;                   // DI/4 = 512 float4 per row
        bf16x4 hv;
        if (row < 96) {
            float4 v = ((const float4*)x_w)[i];
            hv[0]=(bf16_t)v.x; hv[1]=(bf16_t)v.y; hv[2]=(bf16_t)v.z; hv[3]=(bf16_t)v.w;
        } else {
            #pragma unroll
            for (int j = 0; j < 4; ++j) hv[j] = (bf16_t)0.f;
        }
        ((bf16x4*)wxh)[i] = hv;
        return;
    }
    blk -= SPLIT_X_BLKS;
    {                                       // ---- out_proj_w hi ----
        int i = blk * 256 + t;              // over DM*DI/4
        float4 v = ((const float4*)out_w)[i];
        bf16x4 hv;
        hv[0]=(bf16_t)v.x; hv[1]=(bf16_t)v.y; hv[2]=(bf16_t)v.z; hv[3]=(bf16_t)v.w;
        ((bf16x4*)woh)[i] = hv;
    }
}

// --------- split-A/hi-B MFMA NT GEMM, 2-phase double-buffered --------------
// C = (Ah+Al)[M,K] * Bh[N,K]^T ; 2 MFMAs per fragment pair.
// MODE 0: normal tiles + XCD swizzle (needs gridDim.x%8==0, gridDim.y==16).
// MODE 1: x_proj split-K (grid.x = split; N = BN; Cp += split*M*BN).
// MODE 2: out_proj 2-way split-K (grid.x = 16 n-tiles x 2 splits; fp32
//         partials at C + split*M*N; residual handled by reduce_out).
template<int BN, int MODE>
__global__ __launch_bounds__(256) void gemm_mfma(
    const bf16_t* __restrict__ Ah, const bf16_t* __restrict__ Al,
    const bf16_t* __restrict__ Bh,
    float* __restrict__ C, int ldc,
    int M, int N, int K, int kspl)
{
    constexpr int NJ   = BN / 32;
    constexpr int WN   = BN / 2;
    constexpr int ACH  = 8;
    constexpr int BCH  = BN / 16;
    constexpr int NCH  = 2*ACH + BCH;      // 24 (BN=128) / 20 (BN=64)
    constexpr int PERW = NCH / 4;          // 6 / 5
    constexpr int AOFF_L = 128*32;
    constexpr int BOFF_H = 2*128*32;
    constexpr int BUFSZ  = 2*128*32 + BN*32;

    __shared__ bf16_t lds[2*BUFSZ];

    int t = threadIdx.x;
    int w = t >> 6, lane = t & 63;
    int wr = w >> 1, wc = w & 1;

    int m0, n0, k0beg;
    float* Cp = C;
    if (MODE == 0) {                // XCD swizzle (bijective: gx%8==0, gy==16)
        int bid = blockIdx.y * gridDim.x + blockIdx.x;
        int xcd = bid & 7;
        int i   = bid >> 3;
        int bx = xcd * (int)(gridDim.x >> 3) + (i >> 4);
        m0 = (i & 15) * 128;
        n0 = bx * BN;
        k0beg = 0;
    } else if (MODE == 1) {
        m0 = blockIdx.y * 128;
        n0 = 0;
        k0beg = blockIdx.x * kspl;
        Cp += (size_t)blockIdx.x * M * BN;
    } else {                        // MODE 2
        int ntile = blockIdx.x & 15;
        int split = blockIdx.x >> 4;
        m0 = blockIdx.y * 128;
        n0 = ntile * BN;
        k0beg = split * kspl;
        Cp += (size_t)split * M * N;
    }
    int nst = ((MODE == 0) ? K : kspl) >> 5;

    f32x4 acc[4][NJ];
    #pragma unroll
    for (int i = 0; i < 4; ++i)
        #pragma unroll
        for (int j = 0; j < NJ; ++j)
            acc[i][j] = (f32x4){0.f, 0.f, 0.f, 0.f};

    int lrow = lane >> 2;          // row within 16-row chunk
    int lcol = (lane & 3) * 8;     // k element offset
    int ar   = wr*64 + (lane & 15);
    int br   = wc*WN + (lane & 15);
    int koff = (lane >> 4) * 8;

    auto STAGE = [&](int buf, int k0) {
        int base = buf ? BUFSZ : 0;
        #pragma unroll
        for (int q = 0; q < PERW; ++q) {
            int ch = w * PERW + q;
            const bf16_t* g; int le;
            if (ch < ACH) {
                int cc = ch;
                g  = Ah + (size_t)(m0 + cc*16 + lrow)*K + k0 + lcol;
                le = cc*512 + lane*8;
            } else if (ch < 2*ACH) {
                int cc = ch - ACH;
                g  = Al + (size_t)(m0 + cc*16 + lrow)*K + k0 + lcol;
                le = AOFF_L + cc*512 + lane*8;
            } else {
                int cc = ch - 2*ACH;
                g  = Bh + (size_t)(n0 + cc*16 + lrow)*K + k0 + lcol;
                le = BOFF_H + cc*512 + lane*8;
            }
            gload_lds16(g, &lds[base + le]);
        }
    };

    STAGE(0, k0beg);
    __syncthreads();
    int cur = 0;
    for (int s = 0; s < nst; ++s) {
        int k0 = k0beg + (s << 5);
        if (s + 1 < nst) STAGE(cur ^ 1, k0 + 32);
        int base = cur ? BUFSZ : 0;

        bf16x8 ah[4], al4[4], bh[NJ];
        #pragma unroll
        for (int i = 0; i < 4; ++i) {
            ah[i]  = *(const bf16x8*)&lds[base + (ar + i*16)*32 + koff];
            al4[i] = *(const bf16x8*)&lds[base + AOFF_L + (ar + i*16)*32 + koff];
        }
        #pragma unroll
        for (int j = 0; j < NJ; ++j)
            bh[j]  = *(const bf16x8*)&lds[base + BOFF_H + (br + j*16)*32 + koff];
        #pragma unroll
        for (int i = 0; i < 4; ++i)
            #pragma unroll
            for (int j = 0; j < NJ; ++j) {
                acc[i][j] = __builtin_amdgcn_mfma_f32_16x16x32_bf16(ah[i],  bh[j], acc[i][j], 0, 0, 0);
                acc[i][j] = __builtin_amdgcn_mfma_f32_16x16x32_bf16(al4[i], bh[j], acc[i][j], 0, 0, 0);
            }
        __syncthreads();
        cur ^= 1;
    }

    // epilogue: C/D layout col=lane&15, row=(lane>>4)*4+reg  [m89-verified]
    int rb = m0 + wr*64 + (lane >> 4)*4;
    int cb = n0 + wc*WN + (lane & 15);
    #pragma unroll
    for (int i = 0; i < 4; ++i)
        #pragma unroll
        for (int j = 0; j < NJ; ++j) {
            int col = cb + j*16;
            #pragma unroll
            for (int r = 0; r < 4; ++r) {
                int row = rb + i*16 + r;
                Cp[(size_t)row*ldc + col] = acc[i][j][r];
            }
        }
}

// ==== out_proj combine: out = part0 + part1 + x (residual) ================
__global__ __launch_bounds__(256) void reduce_out(
    const float* __restrict__ parts,    // [2][NTOK*DM]
    const float* __restrict__ x,
    float* __restrict__ out)
{
    int i = blockIdx.x * 256 + threadIdx.x;     // over NTOK*DM/4
    float4 a = ((const float4*)parts)[i];
    float4 b = ((const float4*)(parts + (size_t)NTOK*DM))[i];
    float4 xv = ((const float4*)x)[i];
    float4 o;
    o.x = a.x + b.x + xv.x; o.y = a.y + b.y + xv.y;
    o.z = a.z + b.z + xv.z; o.w = a.w + b.w + xv.w;
    ((float4*)out)[i] = o;
}

// ==== x_proj reduce + fused dt_proj matvec (1024 blocks, 4/CU) =============
__global__ __launch_bounds__(256) void dt_fuse(
    const float* __restrict__ parts,
    float* __restrict__ bc,
    const float* __restrict__ dt_w,     // [DI, DR] fp32
    const float* __restrict__ dt_b,     // [DI]
    float* __restrict__ delta)          // [NTOK, DI]
{
    __shared__ float dtsh[4][DR];       // 1 KB
    int blk = blockIdx.x;               // 0..1023
    int hf  = blk & 1;                  // d-half
    int tb  = blk >> 1;                 // token group 0..511
    int t = threadIdx.x;
    if (t < 128) {
        int token = t >> 5;             // 0..3
        int c = (t & 31) * 4;           // 0..124
        int m = tb*4 + token;
        float4 s = {0.f, 0.f, 0.f, 0.f};
        #pragma unroll
        for (int sp = 0; sp < SPLITS; ++sp) {
            float4 v = *(const float4*)(parts + ((size_t)sp*NTOK + m)*128 + c);
            s.x += v.x; s.y += v.y; s.z += v.z; s.w += v.w;
        }
        if (c < 64) {
            *(float4*)&dtsh[token][c] = s;
        } else if (c < 96 && hf == 0) {
            *(float4*)(bc + (size_t)m*32 + (c - 64)) = s;
        }
    }
    __syncthreads();
    for (int dd = 0; dd < 4; ++dd) {
        int d = hf*1024 + dd*256 + t;
        const float4* wp = (const float4*)(dt_w + (size_t)d*DR);
        float bb = dt_b[d];
        float a0 = bb, a1 = bb, a2 = bb, a3 = bb;
        #pragma unroll 4
        for (int k4 = 0; k4 < 16; ++k4) {
            float4 wv = wp[k4];
            a0 = fmaf(wv.x, dtsh[0][k4*4+0], a0);
            a1 = fmaf(wv.x, dtsh[1][k4*4+0], a1);
            a2 = fmaf(wv.x, dtsh[2][k4*4+0], a2);
            a3 = fmaf(wv.x, dtsh[3][k4*4+0], a3);
            a0 = fmaf(wv.y, dtsh[0][k4*4+1], a0);
            a1 = fmaf(wv.y, dtsh[1][k4*4+1], a1);
            a2 = fmaf(wv.y, dtsh[2][k4*4+1], a2);
            a3 = fmaf(wv.y, dtsh[3][k4*4+1], a3);
            a0 = fmaf(wv.z, dtsh[0][k4*4+2], a0);
            a1 = fmaf(wv.z, dtsh[1][k4*4+2], a1);
            a2 = fmaf(wv.z, dtsh[2][k4*4+2], a2);
            a3 = fmaf(wv.z, dtsh[3][k4*4+2], a3);
            a0 = fmaf(wv.w, dtsh[0][k4*4+3], a0);
            a1 = fmaf(wv.w, dtsh[1][k4*4+3], a1);
            a2 = fmaf(wv.w, dtsh[2][k4*4+3], a2);
            a3 = fmaf(wv.w, dtsh[3][k4*4+3], a3);
        }
        delta[(size_t)(tb*4 + 0)*DI + d] = softplusf(a0);
        delta[(size_t)(tb*4 + 1)*DI + d] = softplusf(a1);
        delta[(size_t)(tb*4 + 2)*DI + d] = softplusf(a2);
        delta[(size_t)(tb*4 + 3)*DI + d] = softplusf(a3);
    }
}

// ------- causal depthwise conv (DC=4) + bias + SiLU -> split bf16 ----------
__global__ __launch_bounds__(256) void conv_silu_k(const float* __restrict__ xz,
                                                   const float* __restrict__ cw,
                                                   const float* __restrict__ cb,
                                                   bf16_t* __restrict__ xch,
                                                   bf16_t* __restrict__ xcl)
{
    int idx = blockIdx.x * 256 + threadIdx.x;
    int d4 = idx & (DI/4 - 1);
    int m  = idx >> 9;
    int l  = m & (L_ - 1);
    int d  = d4 * 4;

    float4 w0 = *(const float4*)(cw + (size_t)(d+0)*DC);
    float4 w1 = *(const float4*)(cw + (size_t)(d+1)*DC);
    float4 w2 = *(const float4*)(cw + (size_t)(d+2)*DC);
    float4 w3 = *(const float4*)(cw + (size_t)(d+3)*DC);
    float wr0[4] = {w0.x,w0.y,w0.z,w0.w};
    float wr1[4] = {w1.x,w1.y,w1.z,w1.w};
    float wr2[4] = {w2.x,w2.y,w2.z,w2.w};
    float wr3[4] = {w3.x,w3.y,w3.z,w3.w};
    float4 bias = *(const float4*)(cb + d);
    float a0 = bias.x, a1 = bias.y, a2 = bias.z, a3 = bias.w;

    #pragma unroll
    for (int j = 0; j < DC; ++j) {
        int tt = l - (DC-1) + j;
        if (tt < 0) continue;
        float4 xv = *(const float4*)(xz + (size_t)(m - l + tt)*(2*DI) + d);
        a0 = fmaf(wr0[j], xv.x, a0);
        a1 = fmaf(wr1[j], xv.y, a1);
        a2 = fmaf(wr2[j], xv.z, a2);
        a3 = fmaf(wr3[j], xv.w, a3);
    }
    float o[4] = { siluf(a0), siluf(a1), siluf(a2), siluf(a3) };
    bf16x4 hv, lv;
    #pragma unroll
    for (int j = 0; j < 4; ++j) { hl_t s = split2(o[j]); hv[j] = s.h; lv[j] = s.l; }
    *(bf16x4*)(xch + (size_t)m*DI + d) = hv;
    *(bf16x4*)(xcl + (size_t)m*DI + d) = lv;
}

// ---------------- chunked selective scan (NC=32 chunks of CL=32) -----------
__global__ __launch_bounds__(256) void scan_p1(const float* __restrict__ delta,
                                               const bf16_t* __restrict__ xch,
                                               const bf16_t* __restrict__ xcl,
                                               const float* __restrict__ bc,
                                               const float* __restrict__ A_log,
                                               float* __restrict__ Sbuf,
                                               float* __restrict__ Hbuf)
{
    __shared__ float Bsh[CL][16];
    int t = threadIdx.x;
    int blk = blockIdx.x;                 // b*(NC*8) + c*8 + dblk
    int d = (blk & 7) * 256 + t;
    int c = (blk >> 3) & (NC - 1);
    int b = blk >> 8;
    int m0 = b * L_ + c * CL;

    for (int i = t; i < CL*16; i += 256)
        Bsh[i >> 4][i & 15] = bc[(size_t)(m0 + (i >> 4))*32 + (i & 15)];
    __syncthreads();

    float A[16], h[16];
    #pragma unroll
    for (int j = 0; j < 4; ++j) {
        float4 al = *(const float4*)(A_log + (size_t)d*DS + j*4);
        A[j*4+0] = -__expf(al.x); A[j*4+1] = -__expf(al.y);
        A[j*4+2] = -__expf(al.z); A[j*4+3] = -__expf(al.w);
    }
    #pragma unroll
    for (int n = 0; n < 16; ++n) h[n] = 0.f;
    float S = 0.f;

    #pragma unroll 4
    for (int tt = 0; tt < CL; ++tt) {
        int m = m0 + tt;
        float dv = delta[(size_t)m*DI + d];
        float xv = (float)xch[(size_t)m*DI + d] + (float)xcl[(size_t)m*DI + d];
        float dx = dv * xv;
        S += dv;
        #pragma unroll
        for (int n = 0; n < 16; ++n) {
            float dA = __expf(dv * A[n]);
            h[n] = fmaf(dA, h[n], Bsh[tt][n] * dx);
        }
    }

    Sbuf[(size_t)(b*NC + c)*DI + d] = S;
    size_t o = ((size_t)((b*NC + c)*DI) + d) * DS;
    #pragma unroll
    for (int j = 0; j < 4; ++j) {
        float4 hv;
        hv.x = h[j*4+0]; hv.y = h[j*4+1]; hv.z = h[j*4+2]; hv.w = h[j*4+3];
        *(float4*)(Hbuf + o + j*4) = hv;
    }
}

// Phase 3 (includes former p2): per-block h0 prefix over preceding chunks,
// then replay chunk and emit g = (y + xc*D)*silu(z) as split bf16.
__global__ __launch_bounds__(256) void scan_p3(const float* __restrict__ delta,
                                               const float* __restrict__ xz,
                                               const bf16_t* __restrict__ xch,
                                               const bf16_t* __restrict__ xcl,
                                               const float* __restrict__ bc,
                                               const float* __restrict__ A_log,
                                               const float* __restrict__ Dp,
                                               const float* __restrict__ Sbuf,
                                               const float* __restrict__ Hbuf,
                                               bf16_t* __restrict__ gh,
                                               bf16_t* __restrict__ gl)
{
    __shared__ float Bsh[CL][16];
    __shared__ float Csh[CL][16];
    int t = threadIdx.x;
    int blk = blockIdx.x;
    int d = (blk & 7) * 256 + t;
    int c = (blk >> 3) & (NC - 1);
    int b = blk >> 8;
    int m0 = b * L_ + c * CL;

    for (int i = t; i < CL*16; i += 256) {
        int tt = i >> 4, n = i & 15;
        size_t ro = (size_t)(m0 + tt)*32;
        Bsh[tt][n] = bc[ro + n];
        Csh[tt][n] = bc[ro + 16 + n];
    }
    __syncthreads();

    float A[16], h[16];
    #pragma unroll
    for (int j = 0; j < 4; ++j) {
        float4 al = *(const float4*)(A_log + (size_t)d*DS + j*4);
        A[j*4+0] = -__expf(al.x); A[j*4+1] = -__expf(al.y);
        A[j*4+2] = -__expf(al.z); A[j*4+3] = -__expf(al.w);
    }
    #pragma unroll
    for (int n = 0; n < 16; ++n) h[n] = 0.f;
    for (int j = 0; j < c; ++j) {
        size_t so = (size_t)(b*NC + j)*DI + d;
        float S = Sbuf[so];
        size_t o = so * DS;
        float Hj[16];
        #pragma unroll
        for (int q = 0; q < 4; ++q) {
            float4 hv = *(const float4*)(Hbuf + o + q*4);
            Hj[q*4+0] = hv.x; Hj[q*4+1] = hv.y; Hj[q*4+2] = hv.z; Hj[q*4+3] = hv.w;
        }
        #pragma unroll
        for (int n = 0; n < 16; ++n)
            h[n] = fmaf(__expf(A[n]*S), h[n], Hj[n]);
    }
    float Dreg = Dp[d];

    for (int t0 = 0; t0 < CL; t0 += 4) {
        float dv[4], xv[4], zv[4];
        #pragma unroll
        for (int q = 0; q < 4; ++q) {
            int m = m0 + t0 + q;
            dv[q] = delta[(size_t)m*DI + d];
            xv[q] = (float)xch[(size_t)m*DI + d] + (float)xcl[(size_t)m*DI + d];
            zv[q] = xz[(size_t)m*(2*DI) + DI + d];
        }
        #pragma unroll
        for (int q = 0; q < 4; ++q) {
            int tt = t0 + q, m = m0 + tt;
            float dx = dv[q] * xv[q];
            float y = 0.f;
            #pragma unroll
            for (int n = 0; n < 16; ++n) {
                float dA = __expf(dv[q] * A[n]);
                h[n] = fmaf(dA, h[n], Bsh[tt][n] * dx);
                y = fmaf(h[n], Csh[tt][n], y);
            }
            float gv = (y + xv[q]*Dreg) * siluf(zv[q]);
            hl_t s = split2(gv);
            gh[(size_t)m*DI + d] = s.h;
            gl[(size_t)m*DI + d] = s.l;
        }
    }
}

extern "C" void kernel_launch(void* const* d_in, const int* in_sizes, int n_in,
                              void* d_out, int out_size, void* d_ws, size_t ws_size,
                              hipStream_t stream)
{
    const float* x         = (const float*)d_in[0];
    const float* norm_w    = (const float*)d_in[1];
    const float* in_proj_w = (const float*)d_in[2];
    const float* conv_w    = (const float*)d_in[3];
    const float* conv_b    = (const float*)d_in[4];
    const float* x_proj_w  = (const float*)d_in[5];
    const float* dt_proj_w = (const float*)d_in[6];
    const float* dt_proj_b = (const float*)d_in[7];
    const float* A_log     = (const float*)d_in[8];
    const float* Dp        = (const float*)d_in[9];
    const float* out_proj_w= (const float*)d_in[10];
    float* out = (float*)d_out;

    char* p = (char*)d_ws;
    float*  xz    = (float*)p;  p += (size_t)NTOK*2*DI*4;    // 33.55 MB
    bf16_t* xch   = (bf16_t*)p; p += (size_t)NTOK*DI*2;      //  8.39 MB
    bf16_t* xcl   = (bf16_t*)p; p += (size_t)NTOK*DI*2;      //  8.39 MB
    float*  delta = (float*)p;  p += (size_t)NTOK*DI*4;      // 16.78 MB (-> out partials)
    float*  bc    = (float*)p;  p += (size_t)NTOK*32*4;      //  0.26 MB
    float*  Hbuf  = (float*)p;  p += (size_t)B_*NC*DI*DS*4;  //  8.39 MB (also uh/ul, parts)
    char*   Wreg  = p;          p += (size_t)2*DI*DM*2;      //  8.39 MB (wih -> gh)
    bf16_t* gl    = (bf16_t*)p; p += (size_t)NTOK*DI*2;      //  8.39 MB
    bf16_t* woh   = (bf16_t*)p; p += (size_t)DM*DI*2;        //  4.19 MB
    float*  Sbuf  = (float*)p;  p += (size_t)B_*NC*DI*4;     //  0.52 MB
    bf16_t* wxh   = (bf16_t*)p; p += (size_t)128*DI*2;       //  0.52 MB
    // total ~97.8 MB

    // Hbuf region staged reuse: uh/ul (pre-in_proj) -> parts (x_proj partials)
    // -> H summaries (scan). Wreg: wih (dead after in_proj) -> gh (scan_p3+).
    // delta: read by p1/p3, dead after -> out_proj fp32 partials [2][M*N].
    bf16_t* uh  = (bf16_t*)Hbuf;
    bf16_t* ul  = uh + (size_t)NTOK*DM;
    float*  parts = Hbuf;
    bf16_t* wih = (bf16_t*)Wreg;
    bf16_t* gh  = (bf16_t*)Wreg;
    float*  oparts = delta;

    // 1. RMSNorm + weight hi-casts (one launch)
    rms_split_all<<<NTOK + SPLIT_IN_BLKS + SPLIT_X_BLKS + SPLIT_O_BLKS, 256, 0, stream>>>(
        x, norm_w, uh, ul, in_proj_w, wih, x_proj_w, wxh, out_proj_w, woh);

    // 2. in_proj (MFMA, XCD-swizzled): xz[2048,4096] = u @ in_proj_w^T
    gemm_mfma<128,0><<<dim3((2*DI)/128, NTOK/128), 256, 0, stream>>>(
        uh, ul, wih, xz, 2*DI, NTOK, 2*DI, DM, 0);

    // 3. causal depthwise conv + SiLU -> split bf16 xc
    conv_silu_k<<<(NTOK*(DI/4))/256, 256, 0, stream>>>(xz, conv_w, conv_b, xch, xcl);

    // 4. x_proj (MFMA, split-K over K=2048): parts[8][2048][128]
    gemm_mfma<128,1><<<dim3(SPLITS, NTOK/128), 256, 0, stream>>>(
        xch, xcl, wxh, parts, 128, NTOK, 128, DI, DI/SPLITS);

    // 5. reduce partials + fused dt_proj matvec (fp32), 1024 blocks (4/CU)
    dt_fuse<<<(NTOK/4)*2, 256, 0, stream>>>(parts, bc, dt_proj_w, dt_proj_b, delta);

    // 6. chunked selective scan (p2 folded into p3)
    scan_p1<<<B_*NC*(DI/256), 256, 0, stream>>>(delta, xch, xcl, bc, A_log, Sbuf, Hbuf);
    scan_p3<<<B_*NC*(DI/256), 256, 0, stream>>>(delta, xz, xch, xcl, bc, A_log, Dp,
                                                Sbuf, Hbuf, gh, gl);

    // 7. out_proj (MFMA, 2-way split-K): partials in dead delta region
    gemm_mfma<64,2><<<dim3(32, NTOK/128), 256, 0, stream>>>(
        gh, gl, woh, oparts, DM, NTOK, DM, DI, DI/2);

    // 8. combine partials + residual
    reduce_out<<<(NTOK*DM/4)/256, 256, 0, stream>>>(oparts, x, out);
}